// Round 1
// 237.555 us; speedup vs baseline: 1.0294x; 1.0294x over previous
//
#include <hip/hip_runtime.h>
#include <hip/hip_bf16.h>
#include <cstdint>
#include <cstddef>

typedef __hip_bfloat16 bf16;
typedef __attribute__((ext_vector_type(8))) short short8;
typedef __attribute__((ext_vector_type(4))) short short4v;
typedef __attribute__((ext_vector_type(4))) float floatx4;

// Problem dims (all tensors float32; gates staged bf16)
#define BB 8
#define SS 4096
#define DIN 256
#define DH 512
#define NCH 128
#define CHUNK 32       // NCH*CHUNK == SS

__device__ __forceinline__ float b2f(bf16 v) { return __bfloat162float(v); }
__device__ __forceinline__ float sh2f(short v) {
    unsigned int u = ((unsigned int)(unsigned short)v) << 16;
    float f; __builtin_memcpy(&f, &u, 4); return f;
}
__device__ __forceinline__ float frcp(float x) { return __builtin_amdgcn_rcpf(x); }
__device__ __forceinline__ short f2sh(float a) {
    bf16 bv = __float2bfloat16(a);
    short sv; __builtin_memcpy(&sv, &bv, 2); return sv;
}

// ---------------- kernel 0a: convert x tile (f32) -> Xb (bf16) ---------------
__global__ __launch_bounds__(256) void convert_x(
    const float* __restrict__ X, bf16* __restrict__ Xb)
{
    const int idx = blockIdx.x * 256 + threadIdx.x;   // 4 elements per thread
    float4 v = ((const float4*)X)[idx];
    bf16 o[4] = {__float2bfloat16(v.x), __float2bfloat16(v.y),
                 __float2bfloat16(v.z), __float2bfloat16(v.w)};
    ((short4v*)Xb)[idx] = *(const short4v*)o;
}

// ---------------- kernel 0b: W (f32 [256][512] x4) -> Wt (bf16 [2048][256]) --
// GATE-INTERLEAVED N ordering: row r = y*128 + g*32 + hh  maps to gate g,
// h = y*32 + hh.  Each gemm n-tile (128 rows) thus holds all 4 gates for the
// same 32-wide h group -> chunk carries computable inside the gemm epilogue.
__global__ __launch_bounds__(256) void transpose_w(
    const float* __restrict__ Wi, const float* __restrict__ Wf,
    const float* __restrict__ Wo, const float* __restrict__ Wz,
    bf16* __restrict__ Wt)
{
    int o = blockIdx.x * 256 + threadIdx.x;   // 0..524287
    int r = o >> 8;                           // interleaved n index 0..2047
    int k = o & 255;
    int y = r >> 7;                           // h-group 0..15
    int c = r & 127;
    int g = c >> 5;                           // gate 0..3
    int h = y * 32 + (c & 31);                // 0..511
    const float* W = (g == 0) ? Wi : (g == 1) ? Wf : (g == 2) ? Wo : Wz;
    Wt[o] = __float2bfloat16(W[(size_t)k * DH + h]);
}

// ---------------- kernel 1: MFMA GEMM + bias + act + chunk-carry fusion ------
__device__ __forceinline__ void load16_lds(const bf16* g, short* l)
{
    __builtin_amdgcn_global_load_lds(
        (const __attribute__((address_space(1))) unsigned int*)g,
        (__attribute__((address_space(3))) unsigned int*)l,
        16, 0, 0);
}

__global__ __launch_bounds__(256) void gemm_mfma(
    const bf16* __restrict__ Xb, const bf16* __restrict__ Wt,
    const float* __restrict__ bi, const float* __restrict__ bfv,
    const float* __restrict__ bo, const float* __restrict__ bz,
    bf16* __restrict__ Pi, bf16* __restrict__ Pf,
    bf16* __restrict__ Po, bf16* __restrict__ Pz,
    float* __restrict__ Aa, float* __restrict__ Bca, float* __restrict__ Bna,
    int nb)
{
    // Union: K-loop uses first 16 KB as As/Bs; epilogue reuses the whole
    // buffer as the 128x132(pad) bf16 C-tile (33792 B -> 4 blocks/CU).
    __shared__ __align__(16) short smem[128 * 132];
    short* As = smem;            // 128*32 shorts (8 KB)
    short* Bs = smem + 4096;     // 128*32 shorts (8 KB)

    const int tid  = threadIdx.x;
    const int m0   = blockIdx.x * 128;
    const int y    = blockIdx.y;
    const int n0   = y * 128;
    const int wave = tid >> 6, lane = tid & 63;
    const int wm   = (wave >> 1) * 64, wn = (wave & 1) * 64;
    const int l15  = lane & 15;
    const int q    = lane >> 4;

    floatx4 acc[4][4];
#pragma unroll
    for (int i = 0; i < 4; i++)
#pragma unroll
        for (int j = 0; j < 4; j++) acc[i][j] = (floatx4){0.f, 0.f, 0.f, 0.f};

    const int r_ld = tid >> 2;
    const int c_ld = tid & 3;
    const bf16* agp0 = Xb + (size_t)(m0 + r_ld) * DIN + c_ld * 8;
    const bf16* agp1 = Xb + (size_t)(m0 + 64 + r_ld) * DIN + c_ld * 8;
    const bf16* bgp0 = Wt + (size_t)(n0 + r_ld) * DIN + c_ld * 8;
    const bf16* bgp1 = Wt + (size_t)(n0 + 64 + r_ld) * DIN + c_ld * 8;

    for (int k0 = 0; k0 < DIN; k0 += 32) {
        load16_lds(agp0 + k0, &As[tid * 8]);
        load16_lds(agp1 + k0, &As[2048 + tid * 8]);
        load16_lds(bgp0 + k0, &Bs[tid * 8]);
        load16_lds(bgp1 + k0, &Bs[2048 + tid * 8]);
        __syncthreads();

        short8 af[4], bfr[4];
#pragma unroll
        for (int ti = 0; ti < 4; ti++)
            af[ti] = *(const short8*)&As[(wm + ti * 16 + l15) * 32 + q * 8];
#pragma unroll
        for (int tj = 0; tj < 4; tj++)
            bfr[tj] = *(const short8*)&Bs[(wn + tj * 16 + l15) * 32 + q * 8];
#pragma unroll
        for (int ti = 0; ti < 4; ti++)
#pragma unroll
            for (int tj = 0; tj < 4; tj++)
                acc[ti][tj] = __builtin_amdgcn_mfma_f32_16x16x32_bf16(
                    af[ti], bfr[tj], acc[ti][tj], 0, 0, 0);
        __syncthreads();
    }

    // -------- epilogue: bias + activation -> bf16 -> LDS C-tile [m][132] ----
    // bank pattern for b16 writes: addr/4 = 66*m + c/2 -> (8q + l15/2) mod 32
    // covers 32 distinct banks over the wave => 2-way (free).
#pragma unroll
    for (int ti = 0; ti < 4; ti++) {
        const int mrow = wm + ti * 16 + q * 4;       // tile-local row
#pragma unroll
        for (int tj = 0; tj < 4; tj++) {
            const int cb = wn + tj * 16;             // wave-uniform col base
            const int g  = cb >> 5;                  // gate 0..3 (uniform)
            const int c  = cb + l15;                 // tile-local col
            const float* bp = (g == 0) ? bi : (g == 1) ? bfv
                            : (g == 2) ? bo : bz;
            const float bsv = bp[y * 32 + (c & 31)];
#pragma unroll
            for (int r = 0; r < 4; r++) {
                const float v = acc[ti][tj][r] + bsv;
                float a;
                if (g == 0 || g == 1) {
                    a = __expf(fminf(fmaxf(v, -20.f), 0.f));     // exp(clip)
                } else if (g == 2) {
                    a = frcp(1.f + __expf(-v));                  // sigmoid
                } else {
                    a = 1.f - 2.f * frcp(__expf(2.f * v) + 1.f); // tanh
                }
                smem[(mrow + r) * 132 + c] = f2sh(a);
            }
        }
    }
    __syncthreads();

    const int bidx = m0 / SS;            // pass-local batch (SS % 128 == 0)

    // -------- coalesced copy-out: LDS -> gate planes, 8 B per lane ----------
    // lanes 0..7 -> 64 B contiguous in Pi, lanes 8..15 -> Pf, ... full lines.
    {
        const int cp  = (tid & 31) * 4;              // col base (4 cols, 1 gate)
        const int g2  = cp >> 5;
        const int hb  = y * 32 + (cp & 31);
        bf16* pl = ((g2 == 0) ? Pi : (g2 == 1) ? Pf : (g2 == 2) ? Po : Pz) + hb;
        const int r0 = tid >> 5;
#pragma unroll
        for (int t = 0; t < 16; t++) {
            const int row = t * 8 + r0;
            short4v v = *(const short4v*)&smem[row * 132 + cp];
            *(short4v*)(pl + (size_t)(m0 + row) * DH) = v;
        }
    }

    // -------- fused chunk-carry: 128 chains (4 chunks x 32 h), f32 scan -----
    // Reads the SAME bf16-rounded gates scan_carry used -> identical numerics.
    if (tid < 128) {
        const int hh = tid & 31;
        const int ch = tid >> 5;                     // chunk within m-tile
        float A = 1.f, Bc = 0.f, Bn = 0.f;
        const short* base = &smem[(ch * 32) * 132];
#pragma unroll 8
        for (int s = 0; s < CHUNK; s++) {
            const short* rp = base + s * 132;
            const float iv = sh2f(rp[hh]);
            const float f  = sh2f(rp[32 + hh]);
            const float zv = sh2f(rp[96 + hh]);
            Bc = fmaf(f, Bc, iv * zv);
            Bn = fmaf(f, Bn, iv);
            A *= f;
        }
        const int ch_g = ((m0 % SS) >> 5) + ch;      // batch-local chunk 0..127
        const int hgl  = y * 32 + hh;
        const size_t cidx = (size_t)(ch_g * nb + bidx) * DH + hgl;
        Aa[cidx] = A; Bca[cidx] = Bc; Bna[cidx] = Bn;
    }
}

// ---------------- kernel 3: sequential scan over chunk carries ---------------
__global__ __launch_bounds__(256) void scan_chunks(
    const float* __restrict__ Aa, const float* __restrict__ Bca,
    const float* __restrict__ Bna,
    float* __restrict__ Cs, float* __restrict__ Ns, int nb)
{
    const int t = blockIdx.x * 256 + threadIdx.x;   // b*512+h chain
    float c = 0.f, n = 1.f;
    for (int ch = 0; ch < NCH; ch++) {
        const size_t cidx = (size_t)ch * (nb * DH) + t;
        Cs[cidx] = c; Ns[cidx] = n;                 // state BEFORE chunk ch
        const float A = Aa[cidx];
        c = fmaf(A, c, Bca[cidx]);
        n = fmaf(A, n, Bna[cidx]);
    }
}

// ---------------- kernel 4: replay chunk with true init, emit h (f32) --------
__global__ __launch_bounds__(256) void scan_emit(
    const bf16* __restrict__ Pi, const bf16* __restrict__ Pf,
    const bf16* __restrict__ Po, const bf16* __restrict__ Pz,
    const float* __restrict__ Cs, const float* __restrict__ Ns,
    float* __restrict__ out, int nb)
{
    const int tid = threadIdx.x;
    const int ch  = blockIdx.x * 4 + (tid >> 6);
    const int b   = blockIdx.y;
    const int hg  = (tid & 63) * 8;
    const size_t base = ((size_t)(b * SS + ch * CHUNK)) * DH + hg;
    const size_t cidx = (size_t)(ch * nb + b) * DH + hg;

    float c[8], n[8];
#pragma unroll
    for (int j = 0; j < 2; j++) {
        *(floatx4*)&c[j * 4] = *(const floatx4*)(Cs + cidx + j * 4);
        *(floatx4*)&n[j * 4] = *(const floatx4*)(Ns + cidx + j * 4);
    }

#pragma unroll 4
    for (int s = 0; s < CHUNK; s++) {
        const size_t o = base + (size_t)s * DH;
        short8 i8 = *(const short8*)(Pi + o);
        short8 f8 = *(const short8*)(Pf + o);
        short8 o8 = *(const short8*)(Po + o);
        short8 z8 = *(const short8*)(Pz + o);
        float h[8];
#pragma unroll
        for (int j = 0; j < 8; j++) {
            const float f  = sh2f(f8[j]);
            const float iv = sh2f(i8[j]);
            const float ov = sh2f(o8[j]);
            const float zv = sh2f(z8[j]);
            c[j] = fmaf(f, c[j], iv * zv);
            n[j] = fmaf(f, n[j], iv);
            h[j] = ov * c[j] * frcp(n[j] + 1e-6f);
        }
        *(floatx4*)(out + o)     = *(floatx4*)&h[0];
        *(floatx4*)(out + o + 4) = *(floatx4*)&h[4];
    }
}

// ---------------- launch -----------------------------------------------------
extern "C" void kernel_launch(void* const* d_in, const int* in_sizes, int n_in,
                              void* d_out, int out_size, void* d_ws, size_t ws_size,
                              hipStream_t stream)
{
    const float* x   = (const float*)d_in[0];
    const float* Wi  = (const float*)d_in[1];
    const float* bi  = (const float*)d_in[2];
    const float* Wf  = (const float*)d_in[3];
    const float* bfv = (const float*)d_in[4];
    const float* Wo  = (const float*)d_in[5];
    const float* bo  = (const float*)d_in[6];
    const float* Wz  = (const float*)d_in[7];
    const float* bz  = (const float*)d_in[8];
    float* out = (float*)d_out;

    // ws-adaptive: nb batches per pass.
    int nb = BB;
    while (nb > 1) {
        size_t need = (1u << 20)                         // Wt
                    + (size_t)nb * SS * DIN * 2          // Xb
                    + 4 * (size_t)nb * SS * DH * 2       // Pi,Pf,Po,Pz
                    + 5 * (size_t)NCH * nb * DH * 4;     // scan arrays
        if (need <= ws_size) break;
        nb >>= 1;
    }

    const size_t plane = (size_t)nb * SS * DH;
    bf16* Wt = (bf16*)d_ws;
    bf16* Xb = (bf16*)((char*)d_ws + (1u << 20));
    bf16* Pi = Xb + (size_t)nb * SS * DIN;
    bf16* Pf = Pi + plane;
    bf16* Po = Pf + plane;
    bf16* Pz = Po + plane;
    float* Aa  = (float*)(Pz + plane);
    float* Bca = Aa  + (size_t)NCH * nb * DH;
    float* Bna = Bca + (size_t)NCH * nb * DH;
    float* Cs  = Bna + (size_t)NCH * nb * DH;
    float* Ns  = Cs  + (size_t)NCH * nb * DH;

    transpose_w<<<2048, 256, 0, stream>>>(Wi, Wf, Wo, Wz, Wt);

    for (int b0 = 0; b0 < BB; b0 += nb) {
        const float* Xsrc = x   + (size_t)b0 * SS * DIN;
        float*       Ob   = out + (size_t)b0 * SS * DH;
        convert_x<<<nb * 1024, 256, 0, stream>>>(Xsrc, Xb);
        gemm_mfma<<<dim3(nb * SS / 128, 16), 256, 0, stream>>>(
            Xb, Wt, bi, bfv, bo, bz, Pi, Pf, Po, Pz, Aa, Bca, Bna, nb);
        scan_chunks<<<2 * nb, 256, 0, stream>>>(Aa, Bca, Bna, Cs, Ns, nb);
        scan_emit<<<dim3(NCH / 4, nb), 256, 0, stream>>>(
            Pi, Pf, Po, Pz, Cs, Ns, Ob, nb);
    }
}